// Round 2
// baseline (537.859 us; speedup 1.0000x reference)
//
#include <hip/hip_runtime.h>

// out[B,D] = sum_i k[i] * x[i][B,D]
// x: [6, 16384, 1024] fp32 (d_in[0]), k: [6] fp32 (d_in[1]), out: [16384,1024] fp32
// Pure streaming, zero reuse: 402 MB read + 67 MB write -> ~75 us floor @ 6.3 TB/s.
// Grid-stride (2048 blocks x 256), unroll x2 -> 12 loads in flight/thread.
//
// R0 EXPERIMENT (re-run in R1; previous attempt died to a container-acquire
// infra failure, kernel never executed): nontemporal hints REMOVED
// (single-variable A/B vs 523.9us baseline).
// Theory: nt flag on gfx950 demotes requests to a no-merge/uncached-like TCC
// path -> ~0.9 TB/s despite perfect coalescing, while plain streaming stores
// (fillBufferAligned in the same capture) hit 6.45 TB/s. For a zero-reuse
// stream, cache allocation costs nothing; the bypass path may cost 7x.

typedef float vfloat4 __attribute__((ext_vector_type(4)));

#define PLANE_VEC (16384 * 1024 / 4)   // float4 per plane = 4,194,304
#define BLOCKS 2048
#define TPB 256

__global__ __launch_bounds__(TPB) void multidense_kernel(
    const vfloat4* __restrict__ x,   // [6 * PLANE_VEC]
    const float*   __restrict__ k,   // [6]
    vfloat4* __restrict__ out) {     // [PLANE_VEC]
    const int stride = BLOCKS * TPB;               // 524288
    int i = blockIdx.x * TPB + threadIdx.x;

    const float k0 = k[0], k1 = k[1], k2 = k[2], k3 = k[3], k4 = k[4], k5 = k[5];

    // PLANE_VEC / stride == 8 exactly; unroll 2 -> 4 outer iterations, no tail.
    #pragma unroll
    for (int it = 0; it < 4; ++it) {
        const int ia = i;
        const int ib = i + stride;

        vfloat4 a0 = x[ia + 0 * PLANE_VEC];
        vfloat4 a1 = x[ia + 1 * PLANE_VEC];
        vfloat4 a2 = x[ia + 2 * PLANE_VEC];
        vfloat4 a3 = x[ia + 3 * PLANE_VEC];
        vfloat4 a4 = x[ia + 4 * PLANE_VEC];
        vfloat4 a5 = x[ia + 5 * PLANE_VEC];
        vfloat4 b0 = x[ib + 0 * PLANE_VEC];
        vfloat4 b1 = x[ib + 1 * PLANE_VEC];
        vfloat4 b2 = x[ib + 2 * PLANE_VEC];
        vfloat4 b3 = x[ib + 3 * PLANE_VEC];
        vfloat4 b4 = x[ib + 4 * PLANE_VEC];
        vfloat4 b5 = x[ib + 5 * PLANE_VEC];

        vfloat4 ra = k0*a0 + k1*a1 + k2*a2 + k3*a3 + k4*a4 + k5*a5;
        vfloat4 rb = k0*b0 + k1*b1 + k2*b2 + k3*b3 + k4*b4 + k5*b5;

        out[ia] = ra;
        out[ib] = rb;

        i += 2 * stride;
    }
}

extern "C" void kernel_launch(void* const* d_in, const int* in_sizes, int n_in,
                              void* d_out, int out_size, void* d_ws, size_t ws_size,
                              hipStream_t stream) {
    const vfloat4* x = (const vfloat4*)d_in[0];
    const float*   k = (const float*)d_in[1];
    vfloat4* out = (vfloat4*)d_out;

    multidense_kernel<<<BLOCKS, TPB, 0, stream>>>(x, k, out);
}